// Round 3
// baseline (75.277 us; speedup 1.0000x reference)
//
#include <hip/hip_runtime.h>
#include <math.h>

#ifndef M_PI
#define M_PI 3.14159265358979323846
#endif

namespace {
constexpr int kL = 2048;          // sequence length
constexpr int kB = 16;            // batch
constexpr int kV = 10;            // vocab
constexpr int kChunk = 64;        // queries per block (lane-per-query)
constexpr int kBlock = 256;       // 4 waves split the bins
constexpr int kBins  = 192;       // 19 phases * 10 tokens = 190, padded
constexpr int kBPW   = 48;        // bins per wave
constexpr int kChunksPerSeq = kL / kChunk;   // 32
}

// score(t,s) = A * r_t * r_s * cos(omega*(s-t)+phi) depends on s only through
// bin(s) = (s%19)*10 + token_s  (190 bins). Softmax over s<=t collapses to a
// count-weighted 190-bin sum.
//
// R3 change vs R2: the bin loops previously issued 3-4 wave-uniform ds_reads
// per bin (LDS-pipe bound, ~6.5us/CU of ds issue at 8 waves/CU). Now each
// lane holds its wave's 48-bin slice in registers (lane i <-> bin blo+i,
// loaded with 4 ds_reads total) and the unrolled loops broadcast via
// v_readlane (VALU) instead. Pass 1 caches sc/cnt in 96 VGPRs so pass 2 is
// exp+fma only. Occupancy is grid-limited (512 blocks = 2 waves/SIMD), so
// the extra VGPRs are free.

static __device__ __forceinline__ float rl_f(float v, int l) {
    return __uint_as_float(__builtin_amdgcn_readlane(__float_as_uint(v), (unsigned)l));
}

__global__ __launch_bounds__(kBlock)
void fused_kernel(const int* __restrict__ tokens,
                  const float* __restrict__ pC,  const float* __restrict__ pEps,
                  const float* __restrict__ pV,  const float* __restrict__ pOsc,
                  const float* __restrict__ pGb, const float* __restrict__ pGs,
                  const float* __restrict__ pCa,
                  float* __restrict__ out,
                  float A, float omega, float phi)
{
    __shared__ int   sCnt[kBins];
    __shared__ float sKc[kBins], sKs[kBins], sVv[kBins];
    __shared__ float sM[4][kChunk], sS[4][kChunk], sA[4][kChunk];

    const int tid  = threadIdx.x;
    const int w    = tid >> 6;
    const int lane = tid & 63;
    const int seq  = blockIdx.x / kChunksPerSeq;
    const int t0   = (blockIdx.x % kChunksPerSeq) * kChunk;
    const int* tok = tokens + seq * kL;

    const float c   = pC[0];
    const float eps = pEps[0];
    const float vsc = pV[0];
    const float osc = pOsc[0];
    const float ga  = pGb[0];
    const float gcs = pGs[0];
    const float cam = pCa[0];

    // ---- Bin tables: Kc[p,d] = r_d*cos(omega*p+phi), Ks, Vv[d]; zero cnt ----
    if (tid < kBins) {
        sCnt[tid] = 0;
        float kc = 0.f, ks = 0.f, vv = 0.f;
        if (tid < 190) {
            const int   p  = tid / 10;
            const float df = (float)(tid - p * 10);
            const float h0 = c - eps * df * df;
            const float h1 = -df;
            const float iv = rsqrtf(0.5f * (h0 * h0 + h1 * h1) + 1e-6f);
            const float n0 = h0 * iv;
            const float r  = n0 * rsqrtf(0.5f * n0 * n0 + 1e-6f);
            float sn, cs;
            __sincosf(omega * (float)p + phi, &sn, &cs);
            kc = r * cs; ks = r * sn; vv = (h1 * iv) * vsc;
        }
        sKc[tid] = kc; sKs[tid] = ks; sVv[tid] = vv;
    }
    __syncthreads();

    // ---- Base histogram over s < t0 (cooperative LDS atomics) ----
    for (int s = tid; s < t0; s += kBlock) {
        const int d = tok[s];
        const int p = s % 19;
        atomicAdd(&sCnt[p * 10 + d], 1);
    }
    __syncthreads();

    // ---- Per-lane register slice of this wave's 48 bins ----
    const int blo = w * kBPW;
    const int sl  = blo + ((lane < kBPW) ? lane : 0);
    const float myKc  = sKc[sl];
    const float myKs  = sKs[sl];
    const float myVv  = sVv[sl];
    const float myCnt = (float)sCnt[sl];

    // ---- Per-lane query-side values (lane l <-> query t0+l) ----
    const int   t   = t0 + lane;
    const int   dt  = tok[t];
    const float dft = (float)dt;
    const float h0  = c - eps * dft * dft;
    const float h1  = -dft;
    const float ivh = rsqrtf(0.5f * (h0 * h0 + h1 * h1) + 1e-6f);
    const float hn0 = h0 * ivh;
    const float r_t = hn0 * rsqrtf(0.5f * hn0 * hn0 + 1e-6f);
    const int   pt  = t % 19;
    float snq, csq;
    __sincosf(omega * (float)pt, &snq, &csq);
    const float qc = A * r_t * csq;
    const float qs = A * r_t * snq;
    const int   mybin = pt * 10 + dt;
    const unsigned long long leInc =
        (lane == 63) ? ~0ull : ((1ull << (lane + 1)) - 1ull);

    // ---- Pass 1: masked max; cache sc & inclusive cnt in registers ----
    float scArr[kBPW], cntArr[kBPW];
    float m = -INFINITY;
    #pragma unroll
    for (int i = 0; i < kBPW; ++i) {
        const unsigned long long msk = __ballot(mybin == (blo + i));
        const float cnt = rl_f(myCnt, i) + (float)__popcll(msk & leInc);
        const float sc  = fmaf(qc, rl_f(myKc, i), qs * rl_f(myKs, i));
        scArr[i]  = sc;
        cntArr[i] = cnt;
        m = fmaxf(m, (cnt > 0.f) ? sc : -INFINITY);
    }
    sM[w][lane] = m;
    __syncthreads();
    m = fmaxf(fmaxf(sM[0][lane], sM[1][lane]), fmaxf(sM[2][lane], sM[3][lane]));

    // ---- Pass 2: count-weighted exp accumulation (register-only) ----
    float sum = 0.f, acc = 0.f;
    #pragma unroll
    for (int i = 0; i < kBPW; ++i) {
        const float e  = (cntArr[i] > 0.f) ? __expf(scArr[i] - m) : 0.f;
        const float ce = cntArr[i] * e;
        sum += ce;
        acc = fmaf(ce, rl_f(myVv, i), acc);
    }
    sS[w][lane] = sum;
    sA[w][lane] = acc;
    __syncthreads();

    // ---- Epilogue: wave 0, lane l finishes query t0+l ----
    if (w == 0) {
        sum = (sS[0][lane] + sS[1][lane]) + (sS[2][lane] + sS[3][lane]);
        acc = (sA[0][lane] + sA[1][lane]) + (sA[2][lane] + sA[3][lane]);
        const float attn0 = acc / sum;

        const float h1a  = h1 + osc * attn0;
        const float inv2 = rsqrtf(0.5f * (h0 * h0 + h1a * h1a) + 1e-6f);
        const float n0   = h0 * inv2;
        const float n1   = h1a * inv2;
        const float g0   = n0 * ga + n1 * gcs;
        const float g1   = n0 * (ga - gcs / c) + n1 * gcs;
        const float carry = cam * (fmaxf(g1, 0.0f) - fmaxf(g0, 0.0f)) * n0;
        const float h1b  = h1a + carry;
        const float inv3 = rsqrtf(0.5f * (h0 * h0 + h1b * h1b) + 1e-6f);
        const float rsq2 = 0.70710678118654752f;
        const float o0   = h0  * inv3 * (0.1f * c * rsq2);
        const float o1   = h1b * inv3 * (-c * 0.02f * rsq2);

        float* op = out + (size_t)(seq * kL + t) * kV;
        #pragma unroll
        for (int j = 0; j < kV; ++j) {
            const float dj = (float)j;
            op[j] = fmaf(o0, c - eps * dj * dj, o1 * (-dj));
        }
    }
}

extern "C" void kernel_launch(void* const* d_in, const int* in_sizes, int n_in,
                              void* d_out, int out_size, void* d_ws, size_t ws_size,
                              hipStream_t stream)
{
    (void)in_sizes; (void)n_in; (void)d_ws; (void)ws_size; (void)out_size;

    const int*   tokens = (const int*)d_in[0];
    const float* C      = (const float*)d_in[1];
    const float* eps    = (const float*)d_in[2];
    const float* v      = (const float*)d_in[3];
    const float* o_sc   = (const float*)d_in[4];
    const float* g_base = (const float*)d_in[5];
    const float* g_slope= (const float*)d_in[6];
    const float* c_amp  = (const float*)d_in[7];

    const double omega = 2.0 * M_PI / 19.0;
    const double amp   = log(10.0) / (cos(omega * 0.3) - cos(omega * 0.7));
    const float  attn_scale = (float)(amp * 0.5);   // (1/sqrt2)*(amp/sqrt2)
    const float  phi        = (float)(omega * 10.3);

    const dim3 grid(kB * kChunksPerSeq);            // 512 blocks
    fused_kernel<<<grid, kBlock, 0, stream>>>(
        tokens, C, eps, v, o_sc, g_base, g_slope, c_amp,
        (float*)d_out, attn_scale, (float)omega, phi);
}

// Round 4
// 73.739 us; speedup vs baseline: 1.0209x; 1.0209x over previous
//
#include <hip/hip_runtime.h>
#include <math.h>

#ifndef M_PI
#define M_PI 3.14159265358979323846
#endif

namespace {
constexpr int kL = 2048;          // sequence length
constexpr int kB = 16;            // batch
constexpr int kV = 10;            // vocab
constexpr int kChunk = 64;        // queries per block (lane-per-query)
constexpr int kBlock = 512;       // 8 waves split the 190 bins (24 each)
constexpr int kWaves = 8;
constexpr int kBins  = 192;       // 19 phases * 10 tokens = 190, padded
constexpr int kBPW   = 24;        // bins per wave (8*24 = 192)
constexpr int kChunksPerSeq = kL / kChunk;   // 32
}

// score(t,s) = A * r_t * r_s * cos(omega*(s-t)+phi) depends on s only through
// bin(s) = (s%19)*10 + token_s  (190 bins); softmax over s<=t collapses to a
// count-weighted 190-bin sum (counts: base histogram of s<t0 + in-chunk
// inclusive counts via ballot/popc; lane l <-> query t0+l).
//
// R4 changes (latency attack; R3 showed the bin sweep is NOT the bound):
//  - token loads batched: one int4 per thread issued at kernel entry (1 round
//    trip, in flight during table setup) instead of an 8-deep serial
//    load->atomic chain between barriers.
//  - 512-thread blocks, 8 waves x 24 bins: 16 waves/CU = 4 waves/SIMD
//    (was 2) to hide the remaining chain latencies. launch_bounds(512,4).
//  - epilogue stores coalesced: o0/o1 staged in LDS, 160 threads each write
//    one float4 (was 10 scattered scalar stores per lane of wave 0).

static __device__ __forceinline__ float rl_f(float v, int l) {
    return __uint_as_float(__builtin_amdgcn_readlane(__float_as_uint(v), (unsigned)l));
}

__global__ __launch_bounds__(kBlock, 4)
void fused_kernel(const int* __restrict__ tokens,
                  const float* __restrict__ pC,  const float* __restrict__ pEps,
                  const float* __restrict__ pV,  const float* __restrict__ pOsc,
                  const float* __restrict__ pGb, const float* __restrict__ pGs,
                  const float* __restrict__ pCa,
                  float* __restrict__ out,
                  float A, float omega, float phi)
{
    __shared__ int   sCnt[kBins];
    __shared__ float sKc[kBins], sKs[kBins], sVv[kBins];
    __shared__ float sM[kWaves][kChunk], sS[kWaves][kChunk], sA[kWaves][kChunk];
    __shared__ float sO0[kChunk], sO1[kChunk];

    const int tid  = threadIdx.x;
    const int w    = tid >> 6;
    const int lane = tid & 63;
    const int seq  = blockIdx.x / kChunksPerSeq;
    const int t0   = (blockIdx.x % kChunksPerSeq) * kChunk;
    const int* tok = tokens + seq * kL;

    // Issue ALL global loads up front (independent; stay in flight).
    const int4 tv = *reinterpret_cast<const int4*>(tok + (tid << 2)); // tokens [4*tid..+3]
    const int  dt = tok[t0 + lane];                                   // this lane's query token
    const float c   = pC[0];
    const float eps = pEps[0];
    const float vsc = pV[0];
    const float osc = pOsc[0];
    const float ga  = pGb[0];
    const float gcs = pGs[0];
    const float cam = pCa[0];

    // ---- Bin tables: Kc[p,d] = r_d*cos(omega*p+phi), Ks, Vv[d]; zero cnt ----
    if (tid < kBins) {
        sCnt[tid] = 0;
        float kc = 0.f, ks = 0.f, vv = 0.f;
        if (tid < 190) {
            const int   p  = tid / 10;
            const float df = (float)(tid - p * 10);
            const float h0 = c - eps * df * df;
            const float h1 = -df;
            const float iv = rsqrtf(0.5f * (h0 * h0 + h1 * h1) + 1e-6f);
            const float n0 = h0 * iv;
            const float r  = n0 * rsqrtf(0.5f * n0 * n0 + 1e-6f);
            float sn, cs;
            __sincosf(omega * (float)p + phi, &sn, &cs);
            kc = r * cs; ks = r * sn; vv = (h1 * iv) * vsc;
        }
        sKc[tid] = kc; sKs[tid] = ks; sVv[tid] = vv;
    }
    __syncthreads();

    // ---- Base histogram over s < t0 (tokens already in registers) ----
    if ((tid << 2) < t0) {
        const int s0 = tid << 2;
        atomicAdd(&sCnt[(s0 % 19) * 10 + tv.x], 1);
        atomicAdd(&sCnt[((s0 + 1) % 19) * 10 + tv.y], 1);
        atomicAdd(&sCnt[((s0 + 2) % 19) * 10 + tv.z], 1);
        atomicAdd(&sCnt[((s0 + 3) % 19) * 10 + tv.w], 1);
    }
    __syncthreads();

    // ---- Per-lane register slice of this wave's 24 bins ----
    const int blo = w * kBPW;
    const int sl  = blo + ((lane < kBPW) ? lane : 0);
    const float myKc  = sKc[sl];
    const float myKs  = sKs[sl];
    const float myVv  = sVv[sl];
    const float myCnt = (float)sCnt[sl];

    // ---- Per-lane query-side values (lane l <-> query t0+l) ----
    const int   t   = t0 + lane;
    const float dft = (float)dt;
    const float h0  = c - eps * dft * dft;
    const float h1  = -dft;
    const float ivh = rsqrtf(0.5f * (h0 * h0 + h1 * h1) + 1e-6f);
    const float hn0 = h0 * ivh;
    const float r_t = hn0 * rsqrtf(0.5f * hn0 * hn0 + 1e-6f);
    const int   pt  = t % 19;
    float snq, csq;
    __sincosf(omega * (float)pt, &snq, &csq);
    const float qc = A * r_t * csq;
    const float qs = A * r_t * snq;
    const int   mybin = pt * 10 + dt;
    const unsigned long long leInc =
        (lane == 63) ? ~0ull : ((1ull << (lane + 1)) - 1ull);

    // ---- Pass 1: masked max over this wave's bins; cache sc & cnt ----
    float scArr[kBPW], cntArr[kBPW];
    float m = -INFINITY;
    #pragma unroll
    for (int i = 0; i < kBPW; ++i) {
        const unsigned long long msk = __ballot(mybin == (blo + i));
        const float cnt = rl_f(myCnt, i) + (float)__popcll(msk & leInc);
        const float sc  = fmaf(qc, rl_f(myKc, i), qs * rl_f(myKs, i));
        scArr[i]  = sc;
        cntArr[i] = cnt;
        m = fmaxf(m, (cnt > 0.f) ? sc : -INFINITY);
    }
    sM[w][lane] = m;
    __syncthreads();
    #pragma unroll
    for (int j = 0; j < kWaves; ++j) m = fmaxf(m, sM[j][lane]);

    // ---- Pass 2: count-weighted exp accumulation (register-only) ----
    float sum = 0.f, acc = 0.f;
    #pragma unroll
    for (int i = 0; i < kBPW; ++i) {
        const float e  = (cntArr[i] > 0.f) ? __expf(scArr[i] - m) : 0.f;
        const float ce = cntArr[i] * e;
        sum += ce;
        acc = fmaf(ce, rl_f(myVv, i), acc);
    }
    sS[w][lane] = sum;
    sA[w][lane] = acc;
    __syncthreads();

    // ---- Epilogue: wave 0 finishes query t0+lane, stages o0/o1 in LDS ----
    if (w == 0) {
        sum = 0.f; acc = 0.f;
        #pragma unroll
        for (int j = 0; j < kWaves; ++j) { sum += sS[j][lane]; acc += sA[j][lane]; }
        const float attn0 = acc / sum;

        const float h1a  = h1 + osc * attn0;
        const float inv2 = rsqrtf(0.5f * (h0 * h0 + h1a * h1a) + 1e-6f);
        const float n0   = h0 * inv2;
        const float n1   = h1a * inv2;
        const float g0   = n0 * ga + n1 * gcs;
        const float g1   = n0 * (ga - gcs / c) + n1 * gcs;
        const float carry = cam * (fmaxf(g1, 0.0f) - fmaxf(g0, 0.0f)) * n0;
        const float h1b  = h1a + carry;
        const float inv3 = rsqrtf(0.5f * (h0 * h0 + h1b * h1b) + 1e-6f);
        const float rsq2 = 0.70710678118654752f;
        sO0[lane] = h0  * inv3 * (0.1f * c * rsq2);
        sO1[lane] = h1b * inv3 * (-c * 0.02f * rsq2);
    }
    __syncthreads();

    // ---- Coalesced store: 640 floats per chunk, 160 threads x float4 ----
    if (tid < (kChunk * kV) / 4) {
        const int g = tid << 2;
        float4 o;
        float* po = &o.x;
        #pragma unroll
        for (int k2 = 0; k2 < 4; ++k2) {
            const int gi = g + k2;
            const int q  = (gi * 6554) >> 16;       // gi/10, exact for gi<640
            const int j  = gi - q * 10;
            const float jf = (float)j;
            po[k2] = fmaf(sO0[q], c - eps * jf * jf, -sO1[q] * jf);
        }
        *reinterpret_cast<float4*>(out + (size_t)(seq * kL + t0) * kV + g) = o;
    }
}

extern "C" void kernel_launch(void* const* d_in, const int* in_sizes, int n_in,
                              void* d_out, int out_size, void* d_ws, size_t ws_size,
                              hipStream_t stream)
{
    (void)in_sizes; (void)n_in; (void)d_ws; (void)ws_size; (void)out_size;

    const int*   tokens = (const int*)d_in[0];
    const float* C      = (const float*)d_in[1];
    const float* eps    = (const float*)d_in[2];
    const float* v      = (const float*)d_in[3];
    const float* o_sc   = (const float*)d_in[4];
    const float* g_base = (const float*)d_in[5];
    const float* g_slope= (const float*)d_in[6];
    const float* c_amp  = (const float*)d_in[7];

    const double omega = 2.0 * M_PI / 19.0;
    const double amp   = log(10.0) / (cos(omega * 0.3) - cos(omega * 0.7));
    const float  attn_scale = (float)(amp * 0.5);   // (1/sqrt2)*(amp/sqrt2)
    const float  phi        = (float)(omega * 10.3);

    const dim3 grid(kB * kChunksPerSeq);            // 512 blocks
    fused_kernel<<<grid, kBlock, 0, stream>>>(
        tokens, C, eps, v, o_sc, g_base, g_slope, c_amp,
        (float*)d_out, attn_scale, (float)omega, phi);
}

// Round 5
// 73.078 us; speedup vs baseline: 1.0301x; 1.0090x over previous
//
#include <hip/hip_runtime.h>
#include <math.h>

#ifndef M_PI
#define M_PI 3.14159265358979323846
#endif

namespace {
constexpr int kL = 2048;          // sequence length
constexpr int kB = 16;            // batch
constexpr int kV = 10;            // vocab
constexpr int kChunk = 64;        // queries per block (lane-per-query)
constexpr int kBlock = 512;       // 8 waves split the 190 bins (24 each)
constexpr int kWaves = 8;
constexpr int kBins  = 192;       // 19 phases * 10 tokens = 190, padded
constexpr int kBPW   = 24;        // bins per wave
constexpr int kChunksPerSeq = kL / kChunk;   // 32
}

// score(t,s) = A * r_t * r_s * cos(omega*(s-t)+phi) depends on s only through
// bin(s) = (s%19)*10 + token_s  (190 bins); softmax over s<=t collapses to a
// count-weighted 190-bin sum (base histogram of s<t0 via LDS atomics +
// in-chunk inclusive counts via ballot/popc; lane l <-> query t0+l).
//
// R5 (critical-path attack; discriminates exec-bound vs launch-overhead-bound):
//  - per-wave online softmax: wave-local masked max m_w, partials relative to
//    m_w, ONE barrier, then combine with exp(m_w - m) rescale. Barriers 5 -> 3,
//    no cross-wave stall between max pass and sum pass.
//  - query-side math hoisted before the table phase (overlaps token loads).
//  - epilogue: wave 0 scatter-stores 5x float2 per lane (rows are 8B-aligned);
//    no LDS staging, no final barrier.
//  - histogram: one %19 + wrap-increments; integer bin counting.

static __device__ __forceinline__ float rl_f(float v, int l) {
    return __uint_as_float(__builtin_amdgcn_readlane(__float_as_uint(v), (unsigned)l));
}
static __device__ __forceinline__ int rl_i(int v, int l) {
    return (int)__builtin_amdgcn_readlane((unsigned)v, (unsigned)l);
}

__global__ __launch_bounds__(kBlock, 4)
void fused_kernel(const int* __restrict__ tokens,
                  const float* __restrict__ pC,  const float* __restrict__ pEps,
                  const float* __restrict__ pV,  const float* __restrict__ pOsc,
                  const float* __restrict__ pGb, const float* __restrict__ pGs,
                  const float* __restrict__ pCa,
                  float* __restrict__ out,
                  float A, float omega, float phi)
{
    __shared__ int   sCnt[kBins];
    __shared__ float sKc[kBins], sKs[kBins], sVv[kBins];
    __shared__ float sM[kWaves][kChunk], sS[kWaves][kChunk], sA[kWaves][kChunk];

    const int tid  = threadIdx.x;
    const int w    = tid >> 6;
    const int lane = tid & 63;
    const int seq  = blockIdx.x / kChunksPerSeq;
    const int t0   = (blockIdx.x % kChunksPerSeq) * kChunk;
    const int* tok = tokens + seq * kL;

    // Issue ALL global loads up front (independent; stay in flight).
    const int4 tv = *reinterpret_cast<const int4*>(tok + (tid << 2));
    const int  dt = tok[t0 + lane];                      // this lane's query token
    const float c   = pC[0];
    const float eps = pEps[0];
    const float vsc = pV[0];
    const float osc = pOsc[0];
    const float ga  = pGb[0];
    const float gcs = pGs[0];
    const float cam = pCa[0];

    // ---- Per-lane query-side values (needs only dt + params; hoisted) ----
    const int   t   = t0 + lane;
    const float dft = (float)dt;
    const float h0  = c - eps * dft * dft;
    const float h1  = -dft;
    const float ivh = rsqrtf(0.5f * (h0 * h0 + h1 * h1) + 1e-6f);
    const float hn0 = h0 * ivh;
    const float r_t = hn0 * rsqrtf(0.5f * hn0 * hn0 + 1e-6f);
    const int   pt  = t % 19;
    float snq, csq;
    __sincosf(omega * (float)pt, &snq, &csq);
    const float qc = A * r_t * csq;
    const float qs = A * r_t * snq;
    const int   mybin = pt * 10 + dt;
    const unsigned long long leInc =
        (lane == 63) ? ~0ull : ((1ull << (lane + 1)) - 1ull);

    // ---- Bin tables: Kc[p,d] = r_d*cos(omega*p+phi), Ks, Vv[d]; zero cnt ----
    if (tid < kBins) {
        sCnt[tid] = 0;
        float kc = 0.f, ks = 0.f, vv = 0.f;
        if (tid < 190) {
            const int   p  = tid / 10;
            const float df = (float)(tid - p * 10);
            const float b0 = c - eps * df * df;
            const float b1 = -df;
            const float iv = rsqrtf(0.5f * (b0 * b0 + b1 * b1) + 1e-6f);
            const float n0 = b0 * iv;
            const float r  = n0 * rsqrtf(0.5f * n0 * n0 + 1e-6f);
            float sn, cs;
            __sincosf(omega * (float)p + phi, &sn, &cs);
            kc = r * cs; ks = r * sn; vv = (b1 * iv) * vsc;
        }
        sKc[tid] = kc; sKs[tid] = ks; sVv[tid] = vv;
    }
    __syncthreads();                                     // B1: tables ready

    // ---- Base histogram over s < t0 (tokens already in registers) ----
    const int s0 = tid << 2;
    if (s0 < t0) {
        int p = s0 % 19;
        atomicAdd(&sCnt[p * 10 + tv.x], 1); p = (p == 18) ? 0 : p + 1;
        atomicAdd(&sCnt[p * 10 + tv.y], 1); p = (p == 18) ? 0 : p + 1;
        atomicAdd(&sCnt[p * 10 + tv.z], 1); p = (p == 18) ? 0 : p + 1;
        atomicAdd(&sCnt[p * 10 + tv.w], 1);
    }
    // Slice loads of tables can start now (written before B1).
    const int blo = w * kBPW;
    const int sl  = blo + ((lane < kBPW) ? lane : 0);
    const float myKc = sKc[sl];
    const float myKs = sKs[sl];
    const float myVv = sVv[sl];
    __syncthreads();                                     // B2: histogram ready
    const int myCnt = sCnt[sl];

    // ---- Wave-local pass 1: masked max over this wave's 24 bins ----
    float scArr[kBPW], cntArr[kBPW];
    float m = -INFINITY;
    #pragma unroll
    for (int i = 0; i < kBPW; ++i) {
        const unsigned long long msk = __ballot(mybin == (blo + i));
        const int   ci = rl_i(myCnt, i) + (int)__popcll(msk & leInc);
        const float sc = fmaf(qc, rl_f(myKc, i), qs * rl_f(myKs, i));
        scArr[i]  = sc;
        cntArr[i] = (float)ci;
        m = fmaxf(m, (ci > 0) ? sc : -INFINITY);
    }

    // ---- Wave-local pass 2: partials relative to m_w (no barrier needed) ----
    float sum = 0.f, acc = 0.f;
    #pragma unroll
    for (int i = 0; i < kBPW; ++i) {
        const float e  = (cntArr[i] > 0.f) ? __expf(scArr[i] - m) : 0.f;
        const float ce = cntArr[i] * e;
        sum += ce;
        acc = fmaf(ce, rl_f(myVv, i), acc);
    }
    sM[w][lane] = m;
    sS[w][lane] = sum;
    sA[w][lane] = acc;
    __syncthreads();                                     // B3: partials ready

    // ---- Combine + epilogue + store: wave 0, lane l <-> query t0+l ----
    if (w == 0) {
        float mg = sM[0][lane];
        #pragma unroll
        for (int j = 1; j < kWaves; ++j) mg = fmaxf(mg, sM[j][lane]);
        sum = 0.f; acc = 0.f;
        #pragma unroll
        for (int j = 0; j < kWaves; ++j) {
            const float sc = __expf(sM[j][lane] - mg);   // m_w=-inf -> 0
            sum = fmaf(sS[j][lane], sc, sum);
            acc = fmaf(sA[j][lane], sc, acc);
        }
        const float attn0 = acc / sum;

        const float h1a  = h1 + osc * attn0;
        const float inv2 = rsqrtf(0.5f * (h0 * h0 + h1a * h1a) + 1e-6f);
        const float n0   = h0 * inv2;
        const float n1   = h1a * inv2;
        const float g0   = n0 * ga + n1 * gcs;
        const float g1   = n0 * (ga - gcs / c) + n1 * gcs;
        const float carry = cam * (fmaxf(g1, 0.0f) - fmaxf(g0, 0.0f)) * n0;
        const float h1b  = h1a + carry;
        const float inv3 = rsqrtf(0.5f * (h0 * h0 + h1b * h1b) + 1e-6f);
        const float rsq2 = 0.70710678118654752f;
        const float o0   = h0  * inv3 * (0.1f * c * rsq2);
        const float o1   = h1b * inv3 * (-c * 0.02f * rsq2);

        // 10 outputs per query = 5 aligned float2 stores (row stride 40B).
        float* op = out + (size_t)(seq * kL + t) * kV;
        #pragma unroll
        for (int j = 0; j < kV; j += 2) {
            const float j0 = (float)j, j1 = (float)(j + 1);
            float2 o;
            o.x = fmaf(o0, c - eps * j0 * j0, -o1 * j0);
            o.y = fmaf(o0, c - eps * j1 * j1, -o1 * j1);
            *reinterpret_cast<float2*>(op + j) = o;
        }
    }
}

extern "C" void kernel_launch(void* const* d_in, const int* in_sizes, int n_in,
                              void* d_out, int out_size, void* d_ws, size_t ws_size,
                              hipStream_t stream)
{
    (void)in_sizes; (void)n_in; (void)d_ws; (void)ws_size; (void)out_size;

    const int*   tokens = (const int*)d_in[0];
    const float* C      = (const float*)d_in[1];
    const float* eps    = (const float*)d_in[2];
    const float* v      = (const float*)d_in[3];
    const float* o_sc   = (const float*)d_in[4];
    const float* g_base = (const float*)d_in[5];
    const float* g_slope= (const float*)d_in[6];
    const float* c_amp  = (const float*)d_in[7];

    const double omega = 2.0 * M_PI / 19.0;
    const double amp   = log(10.0) / (cos(omega * 0.3) - cos(omega * 0.7));
    const float  attn_scale = (float)(amp * 0.5);   // (1/sqrt2)*(amp/sqrt2)
    const float  phi        = (float)(omega * 10.3);

    const dim3 grid(kB * kChunksPerSeq);            // 512 blocks
    fused_kernel<<<grid, kBlock, 0, stream>>>(
        tokens, C, eps, v, o_sc, g_base, g_slope, c_amp,
        (float*)d_out, attn_scale, (float)omega, phi);
}